// Round 1
// baseline (119.975 us; speedup 1.0000x reference)
//
#include <hip/hip_runtime.h>
#include <cstdint>

#define NTOK_BLK 64          // tokens per block (one per lane)
#define EMBED    2048
#define NEXP     16
#define WINF     128         // floats per window per token
#define NWIN     (EMBED / WINF)   // 16 windows
#define NTOK_TOTAL (8 * 4096)
#define WOFF     (NTOK_TOTAL * 2) // float offset of indices region in d_out

// global -> LDS async copy, 16B per lane (CK-style addrspace casts)
__device__ __forceinline__ void g2l16(const float* g, float* l) {
    __builtin_amdgcn_global_load_lds(
        (const __attribute__((address_space(1))) void*)(uintptr_t)g,
        (__attribute__((address_space(3))) void*)(uintptr_t)l,
        16, 0, 0);
}

extern "C" __global__ __launch_bounds__(256, 2)
void router_kernel(const float* __restrict__ x,
                   const float* __restrict__ gw,
                   float* __restrict__ out)
{
    // 2 x 32KB double-buffered x tiles: [64 tokens][128 floats], swizzled
    __shared__ float lds[2][NTOK_BLK * WINF];

    const int tid  = threadIdx.x;
    const int lane = tid & 63;
    // wave id, forced uniform so W-dependent gate_w addresses scalarize (s_load)
    const int W    = __builtin_amdgcn_readfirstlane(tid >> 6);
    const int t0   = blockIdx.x * NTOK_BLK;

    const float4* gw4 = (const float4*)gw;

    float acc[NEXP];
#pragma unroll
    for (int e = 0; e < NEXP; ++e) acc[e] = 0.0f;

    // stage one 32KB window into buffer `buf`.
    // LDS is filled LINEARLY in granule order G = it*256 + tid (rule #21);
    // the global SOURCE granule is inverse-swizzled: g = (pos&~7)|((pos^row)&7)
    auto stage = [&](int win, int buf) {
#pragma unroll
        for (int it = 0; it < 8; ++it) {
            const int G   = it * 256 + tid;   // linear granule in tile (16B units)
            const int row = G >> 5;           // local token
            const int pos = G & 31;           // granule slot within row
            const int g   = (pos & ~7) | ((pos ^ row) & 7);
            const float* src = x + (size_t)(t0 + row) * EMBED + win * WINF + g * 4;
            g2l16(src, &lds[buf][G * 4]);
        }
    };

    stage(0, 0);
    __syncthreads();               // drains vmcnt(0): buffer 0 ready

    int cur = 0;
    for (int win = 0; win < NWIN; ++win) {
        if (win + 1 < NWIN) stage(win + 1, cur ^ 1);   // prefetch next window

        const float* buf = lds[cur];
#pragma unroll
        for (int j = 0; j < 8; ++j) {
            const int g   = W * 8 + j;                       // my granule in row
            const int pos = (g & ~7) | ((g ^ lane) & 7);     // swizzled LDS slot
            const float4 x4 = *(const float4*)&buf[lane * WINF + pos * 4];
            const int dbase4 = win * (WINF / 4) + W * 8 + j; // uniform -> s_load
#pragma unroll
            for (int e = 0; e < NEXP; ++e) {
                const float4 w4 = gw4[e * (EMBED / 4) + dbase4];
                acc[e] = fmaf(x4.x, w4.x, acc[e]);
                acc[e] = fmaf(x4.y, w4.y, acc[e]);
                acc[e] = fmaf(x4.z, w4.z, acc[e]);
                acc[e] = fmaf(x4.w, w4.w, acc[e]);
            }
        }
        __syncthreads();           // drains vmcnt+lgkm: next buffer ready, reads done
        cur ^= 1;
    }

    // cross-wave reduction of quarter-dots via LDS (reuse tile memory)
    float* part = (float*)lds;     // [4 waves][64 tokens][16 experts] = 16KB
#pragma unroll
    for (int q = 0; q < 4; ++q) {
        *(float4*)&part[tid * NEXP + q * 4] =
            make_float4(acc[q * 4 + 0], acc[q * 4 + 1], acc[q * 4 + 2], acc[q * 4 + 3]);
    }
    __syncthreads();

    if (W == 0) {
        float tot[NEXP];
#pragma unroll
        for (int e = 0; e < NEXP; ++e) tot[e] = 0.0f;
#pragma unroll
        for (int w = 0; w < 4; ++w) {
#pragma unroll
            for (int q = 0; q < 4; ++q) {
                const float4 p = *(const float4*)&part[(w * 64 + lane) * NEXP + q * 4];
                tot[q * 4 + 0] += p.x;
                tot[q * 4 + 1] += p.y;
                tot[q * 4 + 2] += p.z;
                tot[q * 4 + 3] += p.w;
            }
        }

        // top-2 with lowest-index tie-break (strict >)
        float m1 = tot[0]; int i1 = 0;
#pragma unroll
        for (int e = 1; e < NEXP; ++e) {
            if (tot[e] > m1) { m1 = tot[e]; i1 = e; }
        }
        float m2 = -INFINITY; int i2 = 0;
#pragma unroll
        for (int e = 0; e < NEXP; ++e) {
            const bool sel = (e != i1) && (tot[e] > m2);
            if (sel) { m2 = tot[e]; i2 = e; }
        }

        // normalized top-2 softmax = softmax over the two logits
        const float ed = __expf(m2 - m1);   // <= 1
        const float w1 = 1.0f / (1.0f + ed);
        const float w2 = 1.0f - w1;

        const int t = t0 + lane;
        out[t * 2 + 0] = w1;
        out[t * 2 + 1] = w2;
        out[WOFF + t * 2 + 0] = (float)i1;
        out[WOFF + t * 2 + 1] = (float)i2;
    }
}

extern "C" void kernel_launch(void* const* d_in, const int* in_sizes, int n_in,
                              void* d_out, int out_size, void* d_ws, size_t ws_size,
                              hipStream_t stream) {
    const float* x  = (const float*)d_in[0];   // [8,4096,2048] f32
    const float* gw = (const float*)d_in[1];   // [16,2048] f32
    float* out = (float*)d_out;                // weights[65536] ++ indices-as-f32[65536]

    const int nblocks = NTOK_TOTAL / NTOK_BLK; // 512
    router_kernel<<<dim3(nblocks), dim3(256), 0, stream>>>(x, gw, out);
}